// Round 15
// baseline (22.416 us; speedup 1.0000x reference)
//
#include <hip/hip_runtime.h>
#include <cstdint>

namespace {

constexpr int N    = 20000;   // nodes
constexpr int D    = 128;     // feature dim
constexpr int DEG  = 32;      // neighbors per node
constexpr int BB   = 1024;    // batch
constexpr int T    = 8;       // walk_times
constexpr int NC   = (N + 15) / 16;  // 1250 combined-mask words (2 bits/node)
constexpr int MAXC = 384;     // list bound (true max ~292)

__device__ __forceinline__ uint32_t rotl32(uint32_t x, int n) {
  return (x << n) | (x >> (32 - n));
}

// Threefry-2x32, 20 rounds (Random123 / JAX threefry2x32_p).
__device__ __forceinline__ void threefry2x32(uint32_t k0, uint32_t k1,
                                             uint32_t x0, uint32_t x1,
                                             uint32_t& o0, uint32_t& o1) {
  const uint32_t ks2 = k0 ^ k1 ^ 0x1BD11BDAu;
  x0 += k0; x1 += k1;
#define TF_ROUND(r) { x0 += x1; x1 = rotl32(x1, (r)); x1 ^= x0; }
  TF_ROUND(13) TF_ROUND(15) TF_ROUND(26) TF_ROUND(6)
  x0 += k1;  x1 += ks2 + 1u;
  TF_ROUND(17) TF_ROUND(29) TF_ROUND(16) TF_ROUND(24)
  x0 += ks2; x1 += k0 + 2u;
  TF_ROUND(13) TF_ROUND(15) TF_ROUND(26) TF_ROUND(6)
  x0 += k0;  x1 += k1 + 3u;
  TF_ROUND(17) TF_ROUND(29) TF_ROUND(16) TF_ROUND(24)
  x0 += k1;  x1 += ks2 + 4u;
  TF_ROUND(13) TF_ROUND(15) TF_ROUND(26) TF_ROUND(6)
  x0 += ks2; x1 += k0 + 5u;
#undef TF_ROUND
  o0 = x0; o1 = x1;
}

__device__ __forceinline__ uint32_t rbits(uint32_t k0, uint32_t k1, uint32_t j) {
  uint32_t o0, o1;
  threefry2x32(k0, k1, 0u, j, o0, o1);
  return o0 ^ o1;
}

// Exact jax.random.gumbel f32 pipeline (step 0 only).
__device__ __forceinline__ float gumbel_f32(uint32_t bits) {
  const uint32_t mant = bits >> 9;
  const float u = (mant == 0u) ? 1.17549435e-38f
                               : (__uint_as_float(0x3F800000u | mant) - 1.0f);
  const float inner = -(float)log((double)u);
  return -(float)log((double)inner);
}

// Monotone f32 -> u32 map (finite floats).
__device__ __forceinline__ uint32_t f2ord(float f) {
  const uint32_t b = __float_as_uint(f);
  return (b & 0x80000000u) ? ~b : (b | 0x80000000u);
}

template <int CTRL>
__device__ __forceinline__ uint32_t dppmov(uint32_t v) {
  return (uint32_t)__builtin_amdgcn_update_dpp((int)v, (int)v, CTRL, 0xF, 0xF, false);
}

// Exact wave64 lexicographic argmax of (hi, lo), broadcast to all lanes.
// 6-level DPP max on hi, ballot for tied lanes, readlane payload; multi-lane
// hi-ties (rare) resolve by max lo over tied set — == (max hi, then max lo).
__device__ __forceinline__ void wave_argmax(uint32_t& hi, uint32_t& lo) {
  uint32_t km = hi;
#define RM(CTRL) { const uint32_t o = dppmov<CTRL>(km); if (o > km) km = o; }
  RM(0x111) RM(0x112) RM(0x114) RM(0x118) RM(0x142) RM(0x143)
#undef RM
  km = (uint32_t)__builtin_amdgcn_readlane((int)km, 63);
  uint64_t m = __ballot(hi == km);
  const int l0 = (int)(__ffsll((unsigned long long)m) - 1);
  uint32_t best = (uint32_t)__builtin_amdgcn_readlane((int)lo, l0);
  m &= m - 1;
  while (m) {  // rare: hi tied across lanes -> take max payload (exact)
    const int l = (int)(__ffsll((unsigned long long)m) - 1);
    const uint32_t lv = (uint32_t)__builtin_amdgcn_readlane((int)lo, l);
    if (lv > best) best = lv;
    m &= m - 1;
  }
  hi = km; lo = best;
}

// combined mask helpers: word holds 16 nodes x {cand bit, chosen bit}
__device__ __forceinline__ uint32_t cwd(int n)  { return (uint32_t)n >> 4; }
__device__ __forceinline__ uint32_t cbit(int n) { return 1u << (((uint32_t)n & 15u) << 1); }
// chosen bit = cbit << 1

__global__ __launch_bounds__(64)
void walk_kernel(const float* __restrict__ features,
                 const float* __restrict__ W,
                 const float* __restrict__ bptr,
                 const int*   __restrict__ neighbors,
                 const int*   __restrict__ train_index,
                 int* __restrict__ out)
{
  __shared__ uint32_t comb[NC];   // bit0(cand)/bit1(chosen) per node
  __shared__ int      lst[MAXC];  // in-place candidate list
  __shared__ float    val0[DEG];  // step-0 scores (val==1 afterwards)

  const int lane = threadIdx.x;
  const int r    = blockIdx.x;
  const int self = train_index[r];
  const uint32_t rN = (uint32_t)(r * N);
  const uint64_t lower = (1ULL << lane) - 1ULL;

  int nbj = -1;
  if (lane < DEG) nbj = neighbors[(size_t)self * DEG + lane];

  {  // clear comb (64-bit stores)
    uint64_t* c8 = reinterpret_cast<uint64_t*>(comb);
    for (int i = lane; i < NC / 2; i += 64) c8[i] = 0ull;
  }

  // step keys: jax.random.split(key(42), 8) partitionable; lane k holds key k.
  // NEVER written after init (R8's bug: hidden sk0 assignment).
  uint32_t sk0, sk1;
  threefry2x32(0u, 42u, 0u, (uint32_t)lane, sk0, sk1);

  // ---- step-0 scores (fold order bit-identical to passing versions) ----
  const float bval = bptr[0];
  const float* frow = features + (size_t)self * D;
  float acc = frow[lane] * W[lane] + frow[lane + 64] * W[lane + 64];
  for (int m = 1; m < 64; m <<= 1) acc += __shfl_xor(acc, m);
  const float sx = acc;

  float sval = 0.0f;
  if (lane < DEG) {
    const float* g  = features + (size_t)nbj * D;
    const float* wy = W + D;
    float a = 0.0f;
    for (int d = 0; d < D; d += 4) {
      const float4 f = *reinterpret_cast<const float4*>(g + d);
      const float4 w = *reinterpret_cast<const float4*>(wy + d);
      a += f.x * w.x; a += f.y * w.y; a += f.z * w.z; a += f.w * w.w;
    }
    sval = fmaxf((sx + a) + bval, 0.0f);
  }

  // build step-0 list {c != self : s_c > 0}; dedup via single atomicOr
  bool add0 = false;
  if (lane < DEG && nbj != self && sval > 0.0f) {
    const uint32_t old = atomicOr(&comb[cwd(nbj)], cbit(nbj));
    add0 = !(old & cbit(nbj));
  }
  const uint64_t m0 = __ballot(add0);
  if (add0) {
    const int p = (int)__popcll(m0 & lower);
    lst[p] = nbj; val0[p] = sval;
  }
  int cnt = (int)__popcll(m0);
  if (lane == 0) {
    atomicOr(&comb[cwd(self)], cbit(self) << 1);   // chosen = self_oh
    if (cnt == 0) {  // pre-scan fallback mutates the carry: candi = self_oh
      lst[0] = self; val0[0] = 1.0f;
      atomicOr(&comb[cwd(self)], cbit(self));
    }
  }
  if (cnt == 0) cnt = 1;

  // zombies: chosen nodes retained via adjacency (rare). Static slots (rule #20).
  int zom0 = 0, zom1 = 0, zom2 = 0, zom3 = 0, zmask = 0;
  uint32_t hiP = 0u, loP = 0u;  // pipelined next-step argmax partials
  int  nnNext = 0, posNext = 0; // tail-computed winner for step k+1
  bool haveNext = false;
  int  nbNext = -1;             // its neighbor row, issued at tail

  for (int k = 0; k < T; ++k) {
    int nn, pos; bool haveList;
    int nb = -1;
    if (k == 0) {  // scored head argmax: v = log(s) + gumbel, exact pipeline
      const uint32_t kk0 = (uint32_t)__builtin_amdgcn_readlane((int)sk0, 0);
      const uint32_t kk1 = (uint32_t)__builtin_amdgcn_readlane((int)sk1, 0);
      uint32_t hi = 0u, lo = 0u;
      if (lane < cnt) {  // cnt <= 32
        const int c = lst[lane];
        const float v = (float)log((double)val0[lane])
                      + gumbel_f32(rbits(kk0, kk1, rN + (uint32_t)c));
        hi = f2ord(v); lo = ((0x7FFFFFu - (uint32_t)c) << 9) | (uint32_t)lane;
      }
      wave_argmax(hi, lo);
      haveList = (cnt > 0);
      nn  = haveList ? (int)(0x7FFFFFu - (lo >> 9)) : self;
      pos = (int)(lo & 0x1FFu);
      if (lane < DEG) nb = neighbors[(size_t)nn * DEG + lane];
    } else {       // precomputed at previous tail; nb already in flight
      nn = nnNext; pos = posNext; haveList = haveNext; nb = nbNext;
    }

    if (lane == 0) out[r * (T + 1) + k + 1] = nn;
    if (k == T - 1) break;   // list is dead after the last draw

    if (lane == 0) atomicOr(&comb[cwd(nn)], cbit(nn) << 1);  // chosen |= nn

    float v0f = 1.0f;
    if (k == 0 && haveList) v0f = val0[pos];  // broadcast read (pre-removal)

    // speculative O(1) removal of nn (re-appended below iff stay; order moot)
    if (haveList) {
      const int last = lst[cnt - 1];            // broadcast read
      if (pos != cnt - 1 && lane == 0) lst[pos] = last;
      --cnt;
    }

    // next-step keys (SGPR via readlane)
    const uint32_t nk0 = (uint32_t)__builtin_amdgcn_readlane((int)sk0, k + 1);
    const uint32_t nk1 = (uint32_t)__builtin_amdgcn_readlane((int)sk1, k + 1);

    // pipelined survivor scan for step k+1 — 2-way ILP (two independent
    // threefry chains per iteration); merge is associative max, exact.
    hiP = 0u; loP = 0u;
    uint32_t hi2 = 0u, lo2 = 0u;
    for (int i = lane; i < cnt; i += 128) {
      const int c = lst[i];
      const uint32_t h = rbits(nk0, nk1, rN + (uint32_t)c) >> 9;
      const uint32_t l = ((0x7FFFFFu - (uint32_t)c) << 9) | (uint32_t)i;
      const int i2 = i + 64;
      if (i2 < cnt) {
        const int c2 = lst[i2];
        const uint32_t h2 = rbits(nk0, nk1, rN + (uint32_t)c2) >> 9;
        const uint32_t l2 = ((0x7FFFFFu - (uint32_t)c2) << 9) | (uint32_t)i2;
        if (h2 > hi2 || (h2 == hi2 && l2 > lo2)) { hi2 = h2; lo2 = l2; }
      }
      if (h > hiP || (h == hiP && l > loP)) { hiP = h; loP = l; }
    }
    if (hi2 > hiP || (hi2 == hiP && lo2 > loP)) { hiP = hi2; loP = lo2; }

    // ---- nb-dependent resolution (vmcnt wait lands here) ----
    const bool adNN = __any(nb == nn);
    const bool wasZ = ((zmask & 1) && zom0 == nn) || ((zmask & 2) && zom1 == nn) ||
                      ((zmask & 4) && zom2 == nn) || ((zmask & 8) && zom3 == nn);
    const bool stay = haveList &&
        ((k == 0) ? (((v0f - 1.0f) + (adNN ? 1.0f : 0.0f)) > 0.0f) : adNN);

    if (stay) {  // rare: re-append nn; track as zombie; merge its key
      if (lane == 0) lst[cnt] = nn;
      const int posN = cnt; ++cnt;
      if (!wasZ) {
        if      (!(zmask & 1)) { zom0 = nn; zmask |= 1; }
        else if (!(zmask & 2)) { zom1 = nn; zmask |= 2; }
        else if (!(zmask & 4)) { zom2 = nn; zmask |= 4; }
        else                   { zom3 = nn; zmask |= 8; }
      }
      const uint32_t h = rbits(nk0, nk1, rN + (uint32_t)nn) >> 9;
      const uint32_t l = ((0x7FFFFFu - (uint32_t)nn) << 9) | (uint32_t)posN;
      if (h > hiP || (h == hiP && l > loP)) { hiP = h; loP = l; }
    } else if (wasZ) {  // nn was a zombie and now leaves for good
      if ((zmask & 1) && zom0 == nn) zmask &= ~1;
      else if ((zmask & 2) && zom1 == nn) zmask &= ~2;
      else if ((zmask & 4) && zom2 == nn) zmask &= ~4;
      else if ((zmask & 8) && zom3 == nn) zmask &= ~8;
    }

    // zombie retests (rare, wave-uniform skip): z stays iff z in nb(nn)
    bool zdrop = false;
    if (zmask) {
#define ZTEST(BIT, Z) \
      if ((zmask & BIT) && Z != nn) { \
        if (!__any(nb == Z)) { \
          int pz = -1; \
          for (int i = lane; i < cnt; i += 64) if (lst[i] == Z) pz = i; \
          const uint64_t fz = __ballot(pz >= 0); \
          const int sz = (int)(__ffsll((unsigned long long)fz) - 1); \
          pz = __shfl(pz, sz); \
          const int lastz = lst[cnt - 1]; \
          if (pz != cnt - 1 && lane == 0) lst[pz] = lastz; \
          --cnt; zmask &= ~BIT; zdrop = true; \
        } \
      }
      ZTEST(1, zom0) ZTEST(2, zom1) ZTEST(4, zom2) ZTEST(8, zom3)
#undef ZTEST
    }
    if (zdrop) {  // rare: partials may reference dropped/moved entries — redo
      hiP = 0u; loP = 0u;
      for (int i = lane; i < cnt; i += 64) {
        const int c = lst[i];
        const uint32_t h = rbits(nk0, nk1, rN + (uint32_t)c) >> 9;
        const uint32_t l = ((0x7FFFFFu - (uint32_t)c) << 9) | (uint32_t)i;
        if (h > hiP || (h == hiP && l > loP)) { hiP = h; loP = l; }
      }
    }

    // (b) fresh adj members — ONE atomic: old word tests cand AND chosen bits.
    // (nn's chosen bit was set above; same-wave DS ops complete in order.)
    bool added = false;
    const int nbv = nb;
    if (lane < DEG) {
      const uint32_t old = atomicOr(&comb[cwd(nbv)], cbit(nbv));
      added = !(old & (cbit(nbv) | (cbit(nbv) << 1)));
    }
    const uint64_t ma = __ballot(added);
    const int mypos = cnt + (int)__popcll(ma & lower);
    if (added) {
      lst[mypos] = nbv;
      const uint32_t h = rbits(nk0, nk1, rN + (uint32_t)nbv) >> 9;
      const uint32_t l = ((0x7FFFFFu - (uint32_t)nbv) << 9) | (uint32_t)mypos;
      if (h > hiP || (h == hiP && l > loP)) { hiP = h; loP = l; }
    }
    cnt += (int)__popcll(ma);

    // ---- TAIL: argmax for step k+1 NOW, and issue its neighbor row load —
    // deepens the load's shadow by the next head's work (out/chosen/removal).
    {
      uint32_t hi = hiP, lo = loP;
      wave_argmax(hi, lo);
      haveNext = (cnt > 0);
      nnNext  = haveNext ? (int)(0x7FFFFFu - (lo >> 9)) : self;
      posNext = (int)(lo & 0x1FFu);
      nbNext = -1;
      if (k + 1 < T - 1 && lane < DEG)   // last step never uses its nb
        nbNext = neighbors[(size_t)nnNext * DEG + lane];
    }
  }
  if (lane == 0) out[r * (T + 1)] = self;
}

}  // namespace

extern "C" void kernel_launch(void* const* d_in, const int* in_sizes, int n_in,
                              void* d_out, int out_size, void* d_ws, size_t ws_size,
                              hipStream_t stream) {
  const float* features  = (const float*)d_in[0];
  const float* W         = (const float*)d_in[1];
  const float* b         = (const float*)d_in[2];
  const int*   neighbors = (const int*)d_in[3];
  const int*   tindex    = (const int*)d_in[4];
  int* out = (int*)d_out;

  hipLaunchKernelGGL(walk_kernel, dim3(BB), dim3(64), 0, stream,
                     features, W, b, neighbors, tindex, out);
}

// Round 16
// 22.021 us; speedup vs baseline: 1.0179x; 1.0179x over previous
//
#include <hip/hip_runtime.h>
#include <cstdint>

namespace {

constexpr int N    = 20000;   // nodes
constexpr int D    = 128;     // feature dim
constexpr int DEG  = 32;      // neighbors per node
constexpr int BB   = 1024;    // batch
constexpr int T    = 8;       // walk_times
constexpr int NC   = (N + 15) / 16;  // 1250 combined-mask words (2 bits/node)
constexpr int MAXC = 384;     // list bound (true max ~292)

__device__ __forceinline__ uint32_t rotl32(uint32_t x, int n) {
  return (x << n) | (x >> (32 - n));
}

// Threefry-2x32, 20 rounds (Random123 / JAX threefry2x32_p).
__device__ __forceinline__ void threefry2x32(uint32_t k0, uint32_t k1,
                                             uint32_t x0, uint32_t x1,
                                             uint32_t& o0, uint32_t& o1) {
  const uint32_t ks2 = k0 ^ k1 ^ 0x1BD11BDAu;
  x0 += k0; x1 += k1;
#define TF_ROUND(r) { x0 += x1; x1 = rotl32(x1, (r)); x1 ^= x0; }
  TF_ROUND(13) TF_ROUND(15) TF_ROUND(26) TF_ROUND(6)
  x0 += k1;  x1 += ks2 + 1u;
  TF_ROUND(17) TF_ROUND(29) TF_ROUND(16) TF_ROUND(24)
  x0 += ks2; x1 += k0 + 2u;
  TF_ROUND(13) TF_ROUND(15) TF_ROUND(26) TF_ROUND(6)
  x0 += k0;  x1 += k1 + 3u;
  TF_ROUND(17) TF_ROUND(29) TF_ROUND(16) TF_ROUND(24)
  x0 += k1;  x1 += ks2 + 4u;
  TF_ROUND(13) TF_ROUND(15) TF_ROUND(26) TF_ROUND(6)
  x0 += ks2; x1 += k0 + 5u;
#undef TF_ROUND
  o0 = x0; o1 = x1;
}

__device__ __forceinline__ uint32_t rbits(uint32_t k0, uint32_t k1, uint32_t j) {
  uint32_t o0, o1;
  threefry2x32(k0, k1, 0u, j, o0, o1);
  return o0 ^ o1;
}

// Exact jax.random.gumbel f32 pipeline (step 0 only).
__device__ __forceinline__ float gumbel_f32(uint32_t bits) {
  const uint32_t mant = bits >> 9;
  const float u = (mant == 0u) ? 1.17549435e-38f
                               : (__uint_as_float(0x3F800000u | mant) - 1.0f);
  const float inner = -(float)log((double)u);
  return -(float)log((double)inner);
}

// Monotone f32 -> u32 map (finite floats).
__device__ __forceinline__ uint32_t f2ord(float f) {
  const uint32_t b = __float_as_uint(f);
  return (b & 0x80000000u) ? ~b : (b | 0x80000000u);
}

template <int CTRL>
__device__ __forceinline__ uint32_t dppmov(uint32_t v) {
  return (uint32_t)__builtin_amdgcn_update_dpp((int)v, (int)v, CTRL, 0xF, 0xF, false);
}

// Exact wave64 lexicographic argmax of (hi, lo), broadcast to all lanes.
// 6-level DPP max on hi, ballot for tied lanes, readlane payload; multi-lane
// hi-ties (rare) resolve by max lo over tied set — == (max hi, then max lo).
__device__ __forceinline__ void wave_argmax(uint32_t& hi, uint32_t& lo) {
  uint32_t km = hi;
#define RM(CTRL) { const uint32_t o = dppmov<CTRL>(km); if (o > km) km = o; }
  RM(0x111) RM(0x112) RM(0x114) RM(0x118) RM(0x142) RM(0x143)
#undef RM
  km = (uint32_t)__builtin_amdgcn_readlane((int)km, 63);
  uint64_t m = __ballot(hi == km);
  const int l0 = (int)(__ffsll((unsigned long long)m) - 1);
  uint32_t best = (uint32_t)__builtin_amdgcn_readlane((int)lo, l0);
  m &= m - 1;
  while (m) {  // rare: hi tied across lanes -> take max payload (exact)
    const int l = (int)(__ffsll((unsigned long long)m) - 1);
    const uint32_t lv = (uint32_t)__builtin_amdgcn_readlane((int)lo, l);
    if (lv > best) best = lv;
    m &= m - 1;
  }
  hi = km; lo = best;
}

// combined mask helpers: word holds 16 nodes x {cand bit, chosen bit}
__device__ __forceinline__ uint32_t cwd(int n)  { return (uint32_t)n >> 4; }
__device__ __forceinline__ uint32_t cbit(int n) { return 1u << (((uint32_t)n & 15u) << 1); }
// chosen bit = cbit << 1

__global__ __launch_bounds__(64)
void walk_kernel(const float* __restrict__ features,
                 const float* __restrict__ W,
                 const float* __restrict__ bptr,
                 const int*   __restrict__ neighbors,
                 const int*   __restrict__ train_index,
                 int* __restrict__ out)
{
  __shared__ uint32_t comb[NC];   // bit0(cand)/bit1(chosen) per node
  __shared__ int      lst[MAXC];  // in-place candidate list
  __shared__ float    val0[DEG];  // step-0 scores (val==1 afterwards)

  const int lane = threadIdx.x;
  const int r    = blockIdx.x;
  const int self = train_index[r];
  const uint32_t rN = (uint32_t)(r * N);
  const uint64_t lower = (1ULL << lane) - 1ULL;

  int nbj = -1;
  if (lane < DEG) nbj = neighbors[(size_t)self * DEG + lane];

  {  // clear comb (64-bit stores)
    uint64_t* c8 = reinterpret_cast<uint64_t*>(comb);
    for (int i = lane; i < NC / 2; i += 64) c8[i] = 0ull;
  }

  // step keys: jax.random.split(key(42), 8) partitionable; lane k holds key k.
  // NEVER written after init (R8's bug: hidden sk0 assignment).
  uint32_t sk0, sk1;
  threefry2x32(0u, 42u, 0u, (uint32_t)lane, sk0, sk1);

  // ---- step-0 scores (fold order bit-identical to passing versions) ----
  const float bval = bptr[0];
  const float* frow = features + (size_t)self * D;
  float acc = frow[lane] * W[lane] + frow[lane + 64] * W[lane + 64];
  for (int m = 1; m < 64; m <<= 1) acc += __shfl_xor(acc, m);
  const float sx = acc;

  float sval = 0.0f;
  if (lane < DEG) {
    const float* g  = features + (size_t)nbj * D;
    const float* wy = W + D;
    float a = 0.0f;
    for (int d = 0; d < D; d += 4) {
      const float4 f = *reinterpret_cast<const float4*>(g + d);
      const float4 w = *reinterpret_cast<const float4*>(wy + d);
      a += f.x * w.x; a += f.y * w.y; a += f.z * w.z; a += f.w * w.w;
    }
    sval = fmaxf((sx + a) + bval, 0.0f);
  }

  // build step-0 list {c != self : s_c > 0}; dedup via single atomicOr
  bool add0 = false;
  if (lane < DEG && nbj != self && sval > 0.0f) {
    const uint32_t old = atomicOr(&comb[cwd(nbj)], cbit(nbj));
    add0 = !(old & cbit(nbj));
  }
  const uint64_t m0 = __ballot(add0);
  if (add0) {
    const int p = (int)__popcll(m0 & lower);
    lst[p] = nbj; val0[p] = sval;
  }
  int cnt = (int)__popcll(m0);
  if (lane == 0) {
    atomicOr(&comb[cwd(self)], cbit(self) << 1);   // chosen = self_oh
    if (cnt == 0) {  // pre-scan fallback mutates the carry: candi = self_oh
      lst[0] = self; val0[0] = 1.0f;
      atomicOr(&comb[cwd(self)], cbit(self));
    }
  }
  if (cnt == 0) cnt = 1;

  // zombies: chosen nodes retained via adjacency (rare). Static slots (rule #20).
  int zom0 = 0, zom1 = 0, zom2 = 0, zom3 = 0, zmask = 0;
  uint32_t hiP = 0u, loP = 0u;  // pipelined next-step argmax partials

  for (int k = 0; k < T; ++k) {
    // ---- argmax: hi = sort key, lo = (0x7FFFFF - c)<<9 | pos ----
    // (equal key -> max lo -> min c; pos is payload — unique per c, dedup'd list)
    uint32_t hi, lo;
    if (k == 0) {  // scored: v = log(s) + gumbel, exact f32 pipeline (cnt<=32)
      const uint32_t kk0 = (uint32_t)__builtin_amdgcn_readlane((int)sk0, 0);
      const uint32_t kk1 = (uint32_t)__builtin_amdgcn_readlane((int)sk1, 0);
      hi = 0u; lo = 0u;
      if (lane < cnt) {
        const int c = lst[lane];
        const float v = (float)log((double)val0[lane])
                      + gumbel_f32(rbits(kk0, kk1, rN + (uint32_t)c));
        hi = f2ord(v); lo = ((0x7FFFFFu - (uint32_t)c) << 9) | (uint32_t)lane;
      }
    } else {
      hi = hiP; lo = loP;  // precomputed during step k-1's nb shadow
    }
    wave_argmax(hi, lo);
    const bool haveList = (cnt > 0);
    const int nn  = haveList ? (int)(0x7FFFFFu - (lo >> 9)) : self;
    const int pos = (int)(lo & 0x1FFu);

    if (lane == 0) out[r * (T + 1) + k + 1] = nn;
    if (k == T - 1) break;   // list is dead after the last draw

    // dependent neighbor-row load; overlaps everything until first use of nb
    int nb = -1;
    if (lane < DEG) nb = neighbors[(size_t)nn * DEG + lane];

    if (lane == 0) atomicOr(&comb[cwd(nn)], cbit(nn) << 1);  // chosen |= nn

    float v0f = 1.0f;
    if (k == 0 && haveList) v0f = val0[pos];  // broadcast read (pre-removal)

    // speculative O(1) removal of nn (re-appended below iff stay; order moot)
    if (haveList) {
      const int last = lst[cnt - 1];            // broadcast read
      if (pos != cnt - 1 && lane == 0) lst[pos] = last;
      --cnt;
    }

    // next-step keys (SGPR via readlane)
    const uint32_t nk0 = (uint32_t)__builtin_amdgcn_readlane((int)sk0, k + 1);
    const uint32_t nk1 = (uint32_t)__builtin_amdgcn_readlane((int)sk1, k + 1);

    // pipelined survivor scan for step k+1 — 2-way ILP (two independent
    // threefry chains per iteration; merge is associative max, exact).
    // Runs in nb's shadow.
    hiP = 0u; loP = 0u;
    {
      uint32_t hi2 = 0u, lo2 = 0u;
      for (int i = lane; i < cnt; i += 128) {
        const int c = lst[i];
        const uint32_t h = rbits(nk0, nk1, rN + (uint32_t)c) >> 9;
        const uint32_t l = ((0x7FFFFFu - (uint32_t)c) << 9) | (uint32_t)i;
        const int i2 = i + 64;
        if (i2 < cnt) {
          const int c2 = lst[i2];
          const uint32_t h2 = rbits(nk0, nk1, rN + (uint32_t)c2) >> 9;
          const uint32_t l2 = ((0x7FFFFFu - (uint32_t)c2) << 9) | (uint32_t)i2;
          if (h2 > hi2 || (h2 == hi2 && l2 > lo2)) { hi2 = h2; lo2 = l2; }
        }
        if (h > hiP || (h == hiP && l > loP)) { hiP = h; loP = l; }
      }
      if (hi2 > hiP || (hi2 == hiP && lo2 > loP)) { hiP = hi2; loP = lo2; }
    }

    // ---- nb-dependent resolution (vmcnt wait lands here) ----
    const bool adNN = __any(nb == nn);
    const bool wasZ = ((zmask & 1) && zom0 == nn) || ((zmask & 2) && zom1 == nn) ||
                      ((zmask & 4) && zom2 == nn) || ((zmask & 8) && zom3 == nn);
    const bool stay = haveList &&
        ((k == 0) ? (((v0f - 1.0f) + (adNN ? 1.0f : 0.0f)) > 0.0f) : adNN);

    if (stay) {  // rare: re-append nn; track as zombie; merge its key
      if (lane == 0) lst[cnt] = nn;
      const int posN = cnt; ++cnt;
      if (!wasZ) {
        if      (!(zmask & 1)) { zom0 = nn; zmask |= 1; }
        else if (!(zmask & 2)) { zom1 = nn; zmask |= 2; }
        else if (!(zmask & 4)) { zom2 = nn; zmask |= 4; }
        else                   { zom3 = nn; zmask |= 8; }
      }
      const uint32_t h = rbits(nk0, nk1, rN + (uint32_t)nn) >> 9;
      const uint32_t l = ((0x7FFFFFu - (uint32_t)nn) << 9) | (uint32_t)posN;
      if (h > hiP || (h == hiP && l > loP)) { hiP = h; loP = l; }
    } else if (wasZ) {  // nn was a zombie and now leaves for good
      if ((zmask & 1) && zom0 == nn) zmask &= ~1;
      else if ((zmask & 2) && zom1 == nn) zmask &= ~2;
      else if ((zmask & 4) && zom2 == nn) zmask &= ~4;
      else if ((zmask & 8) && zom3 == nn) zmask &= ~8;
    }

    // zombie retests (rare, wave-uniform skip): z stays iff z in nb(nn)
    bool zdrop = false;
    if (zmask) {
#define ZTEST(BIT, Z) \
      if ((zmask & BIT) && Z != nn) { \
        if (!__any(nb == Z)) { \
          int pz = -1; \
          for (int i = lane; i < cnt; i += 64) if (lst[i] == Z) pz = i; \
          const uint64_t fz = __ballot(pz >= 0); \
          const int sz = (int)(__ffsll((unsigned long long)fz) - 1); \
          pz = __shfl(pz, sz); \
          const int lastz = lst[cnt - 1]; \
          if (pz != cnt - 1 && lane == 0) lst[pz] = lastz; \
          --cnt; zmask &= ~BIT; zdrop = true; \
        } \
      }
      ZTEST(1, zom0) ZTEST(2, zom1) ZTEST(4, zom2) ZTEST(8, zom3)
#undef ZTEST
    }
    if (zdrop) {  // rare: partials may reference dropped/moved entries — redo
      hiP = 0u; loP = 0u;
      for (int i = lane; i < cnt; i += 64) {
        const int c = lst[i];
        const uint32_t h = rbits(nk0, nk1, rN + (uint32_t)c) >> 9;
        const uint32_t l = ((0x7FFFFFu - (uint32_t)c) << 9) | (uint32_t)i;
        if (h > hiP || (h == hiP && l > loP)) { hiP = h; loP = l; }
      }
    }

    // (b) fresh adj members — ONE atomic: old word tests cand AND chosen bits.
    // (nn's chosen bit was set above; same-wave DS ops complete in order.)
    bool added = false;
    const int nbv = nb;
    if (lane < DEG) {
      const uint32_t old = atomicOr(&comb[cwd(nbv)], cbit(nbv));
      added = !(old & (cbit(nbv) | (cbit(nbv) << 1)));
    }
    const uint64_t ma = __ballot(added);
    const int mypos = cnt + (int)__popcll(ma & lower);
    if (added) {
      lst[mypos] = nbv;
      const uint32_t h = rbits(nk0, nk1, rN + (uint32_t)nbv) >> 9;
      const uint32_t l = ((0x7FFFFFu - (uint32_t)nbv) << 9) | (uint32_t)mypos;
      if (h > hiP || (h == hiP && l > loP)) { hiP = h; loP = l; }
    }
    cnt += (int)__popcll(ma);
  }
  if (lane == 0) out[r * (T + 1)] = self;
}

}  // namespace

extern "C" void kernel_launch(void* const* d_in, const int* in_sizes, int n_in,
                              void* d_out, int out_size, void* d_ws, size_t ws_size,
                              hipStream_t stream) {
  const float* features  = (const float*)d_in[0];
  const float* W         = (const float*)d_in[1];
  const float* b         = (const float*)d_in[2];
  const int*   neighbors = (const int*)d_in[3];
  const int*   tindex    = (const int*)d_in[4];
  int* out = (int*)d_out;

  hipLaunchKernelGGL(walk_kernel, dim3(BB), dim3(64), 0, stream,
                     features, W, b, neighbors, tindex, out);
}